// Round 7
// baseline (251.558 us; speedup 1.0000x reference)
//
#include <hip/hip_runtime.h>

typedef __bf16 bf16;
typedef __attribute__((ext_vector_type(8))) __bf16 bf16x8;
typedef __attribute__((ext_vector_type(4))) float f32x4;
typedef __attribute__((ext_vector_type(16))) float f32x16;
typedef __attribute__((ext_vector_type(4))) unsigned short u16x4;
typedef __attribute__((ext_vector_type(2))) int v2i;

#define D_MODEL 1024
#define SEQ     2048
#define NB      4
#define NH      16
#define DK      64
#define MROWS   (NB * SEQ)   // 8192

#define MFMA_BF16 __builtin_amdgcn_mfma_f32_16x16x32_bf16
#define MFMA32    __builtin_amdgcn_mfma_f32_32x32x16_bf16
#define EXP2F(x) __builtin_amdgcn_exp2f(x)
#define QSCALE 0.18033688011112042f   // 0.125 * log2(e)

#define BARRIER() do { asm volatile("" ::: "memory"); \
                       __builtin_amdgcn_s_barrier();  \
                       asm volatile("" ::: "memory"); } while (0)

__device__ __forceinline__ bf16 f2b(float f) {
    union { float f; unsigned u; } c; c.f = f;
    unsigned r = (c.u + 0x7fffu + ((c.u >> 16) & 1u)) >> 16;
    union { unsigned short s; bf16 b; } o; o.s = (unsigned short)r;
    return o.b;
}
__device__ __forceinline__ unsigned short f2u(float f) {
    union { float f; unsigned u; } c; c.f = f;
    return (unsigned short)((c.u + 0x7fffu + ((c.u >> 16) & 1u)) >> 16);
}

__device__ __forceinline__ f32x16 zero16() {
    f32x16 z = {0.f,0.f,0.f,0.f,0.f,0.f,0.f,0.f,
                0.f,0.f,0.f,0.f,0.f,0.f,0.f,0.f};
    return z;
}

template <int N> struct IC { static constexpr int v = N; };

// ---------------------------------------------------------------- prep (fused)
__global__ void prep_kernel(const float* __restrict__ X,
                            const float* __restrict__ Wq, const float* __restrict__ Wk,
                            const float* __restrict__ Wv, const float* __restrict__ Wo,
                            bf16* __restrict__ Xb, bf16* __restrict__ WqkvT,
                            bf16* __restrict__ WoT) {
    __shared__ float tile[32][33];
    const int bid = blockIdx.x;
    if (bid < 8192) {
        int i = bid * 256 + threadIdx.x;
        float4 v = ((const float4*)X)[i];
        u16x4 o; o[0] = f2u(v.x); o[1] = f2u(v.y); o[2] = f2u(v.z); o[3] = f2u(v.w);
        ((u16x4*)Xb)[i] = o;
    } else {
        int r = bid - 8192;
        int w = r >> 10, tl = r & 1023;
        const float* src = (w == 0) ? Wq : (w == 1) ? Wk : (w == 2) ? Wv : Wo;
        bf16* dst = (w == 3) ? WoT : WqkvT + (size_t)w * 1024 * 1024;
        const int n0 = (tl & 31) * 32, k0 = (tl >> 5) * 32;
        const int tx = threadIdx.x & 31, ty = threadIdx.x >> 5;
#pragma unroll
        for (int i = 0; i < 4; i++)
            tile[ty + i * 8][tx] = src[(size_t)(k0 + ty + i * 8) * 1024 + n0 + tx];
        __syncthreads();
#pragma unroll
        for (int i = 0; i < 4; i++)
            dst[(size_t)(n0 + ty + i * 8) * 1024 + k0 + tx] = f2b(tile[tx][ty + i * 8]);
    }
}

// ---------------------------------------------------------------- fused QKV GEMM
// R16: R14's spill-proof geometry (BM=256 BN=128, 8 waves 4Mx2N, acc=64/wave,
// LDS 96KB dbuf) + the m201 per-phase interleave that R14 lacked.
// 4 phases per K-tile, each: {ds-read subtile | stage <=1 half-unit (2 gloads)
// | barrier | lgkmcnt(0) | setprio(1) 8 MFMA setprio(0) | barrier}.
//   P0: read af(ks0)x4 + bfr01(ks0)    | stage a1(kt+1) -> buf^1
//   P1: read bfr23(ks0)                | stage b (kt+1) -> buf^1
//   P2: read af(ks1)x4 + bfr01(ks1)    | (no stage: A-low of THIS buf is
//                                         still being read this phase)
//   P3: read bfr23(ks1)                | stage a0(kt+2) -> buf (A reads done
//                                         at P2 drain+barrier)
// vmcnt(2) once per tile at P3 end (only a0(kt+2)'s 2 loads stay in flight;
// a1/b of kt+1 and everything older proven landed). Never 0 in steady state.
// Region safety: every staged region is past its last reader's lgkm drain
// AND a block barrier (a1->buf^1: read ended (t-1).P2; b->buf^1: ended
// (t-1).P3; a0->buf: ended t.P2).
// Frag liveness peak ~40 VGPR + acc 64 -> no spill possible at the 256 cap.
__global__ __launch_bounds__(512, 2) void gemm_qkv(const bf16* __restrict__ A,
                                                   const bf16* __restrict__ Bt,
                                                   bf16* __restrict__ outQ,
                                                   bf16* __restrict__ outV) {
    __shared__ __align__(16) char lds[98304];   // A: 2x32K at 0, B: 2x16K at 65536

    const int t = threadIdx.x;
    const int wid = t >> 6, lane = t & 63;
    const int ln = lane & 15, qd = lane >> 4;
    const int wm = wid >> 1, wn = wid & 1;      // 4 x 2 wave grid
    const int swk = ln & 7;

    // 768 blocks: bijective XCD swizzle (768 % 8 == 0)
    const int wg = (blockIdx.x & 7) * 96 + (blockIdx.x >> 3);
    const int rowb = wg & 31, colb = wg >> 5;   // 32 rows x 24 cols
    const int row0 = rowb * 256, col0 = colb * 128;
    const bool isQK = (col0 < 2048);

    // staging: global side pre-swizzled, LDS dest linear
    const int srow = t >> 3;                    // 0..63
    const int schunk = (t & 7) ^ (srow & 7);
    const bf16* ga = A  + (size_t)(row0 + srow) * 1024 + schunk * 8;
    const bf16* gb = Bt + (size_t)(col0 + srow) * 1024 + schunk * 8;

    // half-unit stages (2 gloads each)
    auto stageA0 = [&](int kt, int buf) {       // A rows 0..127
#pragma unroll
        for (int c = 0; c < 2; c++)
            __builtin_amdgcn_global_load_lds(
                (const __attribute__((address_space(1))) void*)
                    (ga + (size_t)(c * 64) * 1024 + kt * 64),
                (__attribute__((address_space(3))) void*)
                    (lds + buf * 32768 + c * 8192 + t * 16), 16, 0, 0);
    };
    auto stageA1 = [&](int kt, int buf) {       // A rows 128..255
#pragma unroll
        for (int c = 2; c < 4; c++)
            __builtin_amdgcn_global_load_lds(
                (const __attribute__((address_space(1))) void*)
                    (ga + (size_t)(c * 64) * 1024 + kt * 64),
                (__attribute__((address_space(3))) void*)
                    (lds + buf * 32768 + c * 8192 + t * 16), 16, 0, 0);
    };
    auto stageB = [&](int kt, int buf) {        // B rows 0..127
#pragma unroll
        for (int c = 0; c < 2; c++)
            __builtin_amdgcn_global_load_lds(
                (const __attribute__((address_space(1))) void*)
                    (gb + (size_t)(c * 64) * 1024 + kt * 64),
                (__attribute__((address_space(3))) void*)
                    (lds + 65536 + buf * 16384 + c * 8192 + t * 16), 16, 0, 0);
    };

    // per-lane LDS read bases (XOR-swizzled chunk slots, proven 0-conflict)
    const char* pABase = lds + (wm * 64 + ln) * 128;
    const char* pBBase = lds + 65536 + (wn * 64 + ln) * 128;
    const int cks0 = (qd ^ swk) * 16;
    const int cks1 = ((4 + qd) ^ swk) * 16;

    f32x4 acc[4][4];
#pragma unroll
    for (int i = 0; i < 4; i++)
#pragma unroll
        for (int j = 0; j < 4; j++) acc[i][j] = (f32x4){0.f, 0.f, 0.f, 0.f};

    // ---------------- prologue: a0(0), a1(0), b(0), a0(1)  (8 loads)
    stageA0(0, 0); stageA1(0, 0); stageB(0, 0);
    stageA0(1, 1);
    asm volatile("s_waitcnt vmcnt(2)" ::: "memory");   // K0 landed; a0(1) in flight
    BARRIER();

    auto ktile = [&](auto bufc, int kt) {
        constexpr int BUF = decltype(bufc)::v;
        const char* pa0 = pABase + BUF * 32768 + cks0;
        const char* pa1 = pABase + BUF * 32768 + cks1;
        const char* pb0 = pBBase + BUF * 16384 + cks0;
        const char* pb1 = pBBase + BUF * 16384 + cks1;

        bf16x8 af[4], bf01[2], bf23[2];

        auto mfma8 = [&](const bf16x8 (&bp)[2], int j0) {
            __builtin_amdgcn_s_setprio(1);
            if (isQK) {
#pragma unroll
                for (int i = 0; i < 4; i++)
#pragma unroll
                    for (int j = 0; j < 2; j++)
                        acc[i][j0 + j] = MFMA_BF16(bp[j], af[i], acc[i][j0 + j], 0, 0, 0);
            } else {
#pragma unroll
                for (int i = 0; i < 4; i++)
#pragma unroll
                    for (int j = 0; j < 2; j++)
                        acc[i][j0 + j] = MFMA_BF16(af[i], bp[j], acc[i][j0 + j], 0, 0, 0);
            }
            __builtin_amdgcn_s_setprio(0);
        };

        // ---- P0: read af(ks0)+bf01(ks0); stage a1(kt+1)
#pragma unroll
        for (int i = 0; i < 4; i++) af[i] = *(const bf16x8*)(pa0 + i * 2048);
#pragma unroll
        for (int j = 0; j < 2; j++) bf01[j] = *(const bf16x8*)(pb0 + j * 2048);
        if (kt + 1 < 16) stageA1(kt + 1, BUF ^ 1);
        BARRIER();
        asm volatile("s_waitcnt lgkmcnt(0)" ::: "memory");
        mfma8(bf01, 0);
        BARRIER();

        // ---- P1: read bf23(ks0); stage b(kt+1)
#pragma unroll
        for (int j = 0; j < 2; j++) bf23[j] = *(const bf16x8*)(pb0 + (2 + j) * 2048);
        if (kt + 1 < 16) stageB(kt + 1, BUF ^ 1);
        BARRIER();
        asm volatile("s_waitcnt lgkmcnt(0)" ::: "memory");
        mfma8(bf23, 2);
        BARRIER();

        // ---- P2: read af(ks1)+bf01(ks1); no stage
#pragma unroll
        for (int i = 0; i < 4; i++) af[i] = *(const bf16x8*)(pa1 + i * 2048);
#pragma unroll
        for (int j = 0; j < 2; j++) bf01[j] = *(const bf16x8*)(pb1 + j * 2048);
        BARRIER();
        asm volatile("s_waitcnt lgkmcnt(0)" ::: "memory");
        mfma8(bf01, 0);
        BARRIER();

        // ---- P3: read bf23(ks1); stage a0(kt+2) (A reads of BUF done at P2)
#pragma unroll
        for (int j = 0; j < 2; j++) bf23[j] = *(const bf16x8*)(pb1 + (2 + j) * 2048);
        if (kt + 2 < 16) stageA0(kt + 2, BUF);
        BARRIER();
        asm volatile("s_waitcnt lgkmcnt(0)" ::: "memory");
        mfma8(bf23, 2);
        // counted drain: a1(kt+1), b(kt+1) and older must be landed;
        // only a0(kt+2)'s 2 loads stay in flight.
        if (kt + 2 < 16) {
            asm volatile("s_waitcnt vmcnt(2)" ::: "memory");
        } else if (kt + 1 < 16) {
            asm volatile("s_waitcnt vmcnt(0)" ::: "memory");
        }
        BARRIER();
    };

#pragma unroll 1
    for (int kt = 0; kt < 16; kt += 2) {
        ktile(IC<0>{}, kt);
        ktile(IC<1>{}, kt + 1);
    }

    // ---------------- epilogue (4Mx2N wave grid)
    if (isQK) {
#pragma unroll
        for (int i = 0; i < 4; i++)
#pragma unroll
            for (int j = 0; j < 4; j++) {
                int m  = row0 + wm * 64 + i * 16 + ln;
                int n0 = col0 + wn * 64 + j * 16 + qd * 4;
                float scale = (n0 < 1024) ? QSCALE : 1.0f;
                int b = m >> 11, s = m & 2047;
                int h = (n0 & 1023) >> 6, d0 = n0 & 63;
                size_t addr = (((size_t)(b * NH + h) * SEQ + s) * DK + d0)
                              + (size_t)(n0 >> 10) * 8388608;
                u16x4 w;
#pragma unroll
                for (int r = 0; r < 4; r++) w[r] = f2u(acc[i][j][r] * scale);
                *(u16x4*)&outQ[addr] = w;
            }
    } else {
#pragma unroll
        for (int i = 0; i < 4; i++)
#pragma unroll
            for (int j = 0; j < 4; j++) {
                int m0 = row0 + wm * 64 + i * 16 + qd * 4;
                int n  = col0 + wn * 64 + j * 16 + ln - 2048;
                int b = m0 >> 11, s0 = m0 & 2047;
                int h = n >> 6, d = n & 63;
                size_t addr = ((size_t)(b * NH + h) * DK + d) * SEQ + s0;
                u16x4 w;
#pragma unroll
                for (int r = 0; r < 4; r++) w[r] = f2u(acc[i][j][r]);
                *(u16x4*)&outV[addr] = w;
            }
    }
}

// ---------------------------------------------------------------- output GEMM
__global__ __launch_bounds__(256) void gemm_o(const bf16* __restrict__ A,
                                              const bf16* __restrict__ Bt,
                                              float* __restrict__ out) {
    __shared__ __align__(16) bf16 lA[128 * 64];
    __shared__ __align__(16) bf16 lB[128 * 64];

    const int t = threadIdx.x;
    const int wid = t >> 6, lane = t & 63;
    const int ln = lane & 15, qd = lane >> 4;
    const int wm = wid >> 1, wn = wid & 1;

    const int bid = blockIdx.x;
    const int colb = bid & 7, rowb = bid >> 3;
    const int row0 = rowb * 128, col0 = colb * 128;

    const int srow = t >> 3;
    const int schunk = (t & 7) ^ (srow & 7);
    const bf16* ga = A  + (size_t)(row0 + srow) * 1024 + schunk * 8;
    const bf16* gb = Bt + (size_t)(col0 + srow) * 1024 + schunk * 8;
    const int swk = ln & 7;

    f32x4 acc[4][4];
#pragma unroll
    for (int i = 0; i < 4; i++)
#pragma unroll
        for (int j = 0; j < 4; j++) acc[i][j] = (f32x4){0.f, 0.f, 0.f, 0.f};

    for (int kb = 0; kb < 1024; kb += 64) {
#pragma unroll
        for (int c = 0; c < 4; c++) {
            __builtin_amdgcn_global_load_lds(
                (const __attribute__((address_space(1))) void*)(ga + kb + (size_t)c * 32 * 1024),
                (__attribute__((address_space(3))) void*)(&lA[t * 8 + c * 2048]), 16, 0, 0);
            __builtin_amdgcn_global_load_lds(
                (const __attribute__((address_space(1))) void*)(gb + kb + (size_t)c * 32 * 1024),
                (__attribute__((address_space(3))) void*)(&lB[t * 8 + c * 2048]), 16, 0, 0);
        }
        __syncthreads();

#pragma unroll
        for (int ks = 0; ks < 2; ks++) {
            bf16x8 af[4], bfr[4];
#pragma unroll
            for (int i = 0; i < 4; i++)
                af[i] = *(const bf16x8*)&lA[(wm * 64 + i * 16 + ln) * 64
                                            + ((ks * 4 + qd) ^ swk) * 8];
#pragma unroll
            for (int j = 0; j < 4; j++)
                bfr[j] = *(const bf16x8*)&lB[(wn * 64 + j * 16 + ln) * 64
                                             + ((ks * 4 + qd) ^ swk) * 8];
#pragma unroll
            for (int i = 0; i < 4; i++)
#pragma unroll
                for (int j = 0; j < 4; j++)
                    acc[i][j] = MFMA_BF16(bfr[j], af[i], acc[i][j], 0, 0, 0);
        }
        __syncthreads();
    }

#pragma unroll
    for (int i = 0; i < 4; i++)
#pragma unroll
        for (int j = 0; j < 4; j++) {
            int m  = row0 + wm * 64 + i * 16 + ln;
            int n0 = col0 + wn * 64 + j * 16 + qd * 4;
            *(f32x4*)&out[(size_t)m * 1024 + n0] = acc[i][j];
        }
}

// ---------------------------------------------------------------- attention
// R10 structure (unchanged): 32x32 MFMA, in-register softmax via
// cvt_pk_bf16 + permlane32_swap, 64-row q-groups paired (g, 31-g),
// 128-thread blocks, wave-uniform full/edge specialization.
__global__ __launch_bounds__(128, 2) void attn_kernel(const bf16* __restrict__ Q,
                                                      const bf16* __restrict__ K,
                                                      const bf16* __restrict__ Vt,
                                                      bf16* __restrict__ attn_out) {
    // layout: K buf0 | K buf1 | V buf0 | V buf1   (8 KB each)
    __shared__ __align__(16) bf16 smem[4][64 * 64];

    const int t = threadIdx.x;
    const int wid = t >> 6, lane = t & 63;
    const int qcol = lane & 31, h = lane >> 5;

    const int bid = blockIdx.x;
    const int bh = ((bid >> 7) << 3) | (bid & 7);    // XCD-pinned per bh
    const int p  = (bid >> 3) & 15;
    const int gA = 31 - p, gB = p;                   // pair sums to 33 steps
    const int ntA = gA + 1;                          // tiles in phase A

    const bf16* Qh = Q  + (size_t)bh * SEQ * DK;
    const bf16* Kh = K  + (size_t)bh * SEQ * DK;
    const bf16* Vh = Vt + (size_t)bh * DK * SEQ;

    // staging pointers (global side pre-swizzled; LDS dest linear)
    const int srow = t >> 3;                         // 0..15
    const int schunk = (t & 7) ^ (srow & 7);
    const bf16* kgp = Kh + (size_t)srow * DK + schunk * 8;
    const bf16* vgp = Vh + (size_t)srow * SEQ + schunk * 8;

    // per-lane ds-read byte addresses: row=qcol, slot XOR-swizzled
    const char* sbase = (const char*)&smem[0][0];
    int raddr[4];
#pragma unroll
    for (int tt = 0; tt < 4; tt++)
        raddr[tt] = qcol * 128 + (((2 * tt + h) ^ (lane & 7)) * 16);

    int qw0;
    bf16x8 qf[4];
    f32x16 o[2];
    float l;

    auto initGroup = [&](int g) {
        qw0 = g * 64 + wid * 32;
#pragma unroll
        for (int tt = 0; tt < 4; tt++)
            qf[tt] = *(const bf16x8*)(Qh + (size_t)(qw0 + qcol) * DK + tt * 16 + h * 8);
        o[0] = zero16(); o[1] = zero16();
        l = 0.f;
    };

    const int b = bh >> 4, head = bh & 15;
    auto finalize = [&]() {
        float ll = l + __shfl_xor(l, 32);
        const float inv = 1.0f / ll;
        const size_t orow = ((size_t)(b * SEQ + qw0 + qcol)) * D_MODEL + head * DK;
#pragma unroll
        for (int m = 0; m < 2; m++)
#pragma unroll
            for (int q4 = 0; q4 < 4; q4++) {
                u16x4 w;
#pragma unroll
                for (int c = 0; c < 4; c++) w[c] = f2u(o[m][q4 * 4 + c] * inv);
                *(u16x4*)&attn_out[orow + m * 32 + q4 * 8 + h * 4] = w;
            }
    };

    auto stage = [&](int kb, int buf) {
#pragma unroll
        for (int c = 0; c < 4; c++) {
            __builtin_amdgcn_global_load_lds(
                (const __attribute__((address_space(1))) void*)(kgp + (size_t)(kb + c * 16) * DK),
                (__attribute__((address_space(3))) void*)(&smem[buf][t * 8 + c * 1024]), 16, 0, 0);
            __builtin_amdgcn_global_load_lds(
                (const __attribute__((address_space(1))) void*)(vgp + (size_t)c * 16 * SEQ + kb),
                (__attribute__((address_space(3))) void*)(&smem[2 + buf][t * 8 + c * 1024]), 16, 0, 0);
        }
    };

    // QK^T for one 32-wide k-tile: lane=q, reg=k
    auto qkt = [&](const char* kb_base) -> f32x16 {
        f32x16 z = zero16();
#pragma unroll
        for (int tt = 0; tt < 4; tt++) {
            bf16x8 kf = *(const bf16x8*)(kb_base + raddr[tt]);
            z = MFMA32(kf, qf[tt], z, 0, 0, 0);
        }
        return z;
    };

    // pack 8 P-floats (k-slice ks) -> B-fragment, 2 PV MFMAs
    auto pvks = [&](const f32x16& s, int b8, int ks, const char* vbase) {
        unsigned A, B, C, D;
        asm("v_cvt_pk_bf16_f32 %0, %1, %2"
            : "=v"(A) : "v"(s[b8 + 0]), "v"(s[b8 + 1]));
        asm("v_cvt_pk_bf16_f32 %0, %1, %2"
            : "=v"(B) : "v"(s[b8 + 2]), "v"(s[b8 + 3]));
        asm("v_cvt_pk_bf16_f32 %0, %1, %2"
            : "=v"(C) : "v"(s[b8 + 4]), "v"(s[b8 + 5]));
        asm("v_cvt_pk_bf16_f32 %0, %1, %2"
            : "=v"(D) : "v"(s[b8 + 6]), "v"(s[b8 + 7]));
        v2i r02 = __builtin_amdgcn_permlane32_swap((int)A, (int)C, false, false);
        v2i r13 = __builtin_amdgcn_permlane32_swap((int)B, (int)D, false, false);
        union { unsigned u[4]; bf16x8 v; } pf;
        pf.u[0] = (unsigned)r02[0];
        pf.u[1] = (unsigned)r13[0];
        pf.u[2] = (unsigned)r02[1];
        pf.u[3] = (unsigned)r13[1];
#pragma unroll
        for (int m = 0; m < 2; m++) {
            bf16x8 vf = *(const bf16x8*)(vbase + raddr[ks] + m * 4096);
            o[m] = MFMA32(vf, pf.v, o[m], 0, 0, 0);
        }
    };

    auto smaxFull = [&](f32x16& s) -> float {
#pragma unroll
        for (int r = 0; r < 16; r++) s[r] = EXP2F(s[r]);
        float s0 = (s[0] + s[1]) + (s[2] + s[3]);
        float s1 = (s[4] + s[5]) + (s[6] + s[7]);
        float s2 = (s[8] + s[9]) + (s[10] + s[11]);
        float s3 = (s[12] + s[13]) + (s[14] + s[15]);
        return (s0 + s1) + (s2 + s3);
    };

    auto compute = [&](auto curc, int kb) {
        constexpr int CUR = decltype(curc)::v;
        const char* kbase = sbase + CUR * 8192;
        const char* vbase = sbase + 16384 + CUR * 8192;
        const int rel = qw0 - kb;          // wave-uniform
        if (rel < 0) return;
        if (rel >= 64) {
            // ---- full: both tiles, no causal mask
            __builtin_amdgcn_s_setprio(1);
            f32x16 s0 = qkt(kbase);
            f32x16 s1 = qkt(kbase + 4096);
            __builtin_amdgcn_s_setprio(0);
            l += smaxFull(s0);
            __builtin_amdgcn_s_setprio(1);
            pvks(s0, 0, 0, vbase);
            pvks(s0, 8, 1, vbase);
            __builtin_amdgcn_s_setprio(0);
            l += smaxFull(s1);
            __builtin_amdgcn_s_setprio(1);
            pvks(s1, 0, 2, vbase);
            pvks(s1, 8, 3, vbase);
            __builtin_amdgcn_s_setprio(0);
        } else {
            // ---- edge: nt tiles, diagonal mask on tile n = rel>>5
            const int nt = (rel >> 5) + 1;      // 1 or 2
            f32x16 st[2];
#pragma unroll
            for (int n = 0; n < 2; n++)
                if (n < nt) st[n] = qkt(kbase + n * 4096);
            float ps = 0.f;
#pragma unroll
            for (int n = 0; n < 2; n++)
                if (n < nt) {
                    const bool diag = (rel == 32 * n);
#pragma unroll
                    for (int r = 0; r < 16; r++) {
                        float pv = EXP2F(st[n][r]);
                        if (diag) {
                            const int kloc = (r & 3) + 8 * (r >> 2) + 4 * h;
                            pv = (kloc > qcol) ? 0.f : pv;
                        }
                        st[n][r] = pv;
                    }
                    float s0 = (st[n][0] + st[n][1]) + (st[n][2] + st[n][3]);
                    float s1 = (st[n][4] + st[n][5]) + (st[n][6] + st[n][7]);
                    float s2 = (st[n][8] + st[n][9]) + (st[n][10] + st[n][11]);
                    float s3 = (st[n][12] + st[n][13]) + (st[n][14] + st[n][15]);
                    ps += (s0 + s1) + (s2 + s3);
                }
            l += ps;
#pragma unroll
            for (int ks = 0; ks < 4; ks++)
                if (ks < 2 * nt)
                    pvks(st[ks >> 1], (ks & 1) * 8, ks, vbase);
        }
    };

    auto step = [&](auto curc, int i) {
        constexpr int CUR = decltype(curc)::v;
        __syncthreads();                       // drains prev stage (vmcnt(0))
        const int nx = i + 1;
        if (nx < 33) {
            const int tnx = (nx < ntA) ? nx : nx - ntA;
            stage(tnx * 64, CUR ^ 1);
        }
        const int kb = ((i < ntA) ? i : i - ntA) * 64;
        compute(curc, kb);
        if (i == ntA - 1) { finalize(); initGroup(gB); }
    };

    stage(0, 0);
    initGroup(gA);

    step(IC<0>{}, 0);
#pragma unroll 1
    for (int ii = 0; ii < 16; ii++) {
        step(IC<1>{}, 2 * ii + 1);
        step(IC<0>{}, 2 * ii + 2);
    }
    finalize();
}

// ---------------------------------------------------------------- launch
extern "C" void kernel_launch(void* const* d_in, const int* in_sizes, int n_in,
                              void* d_out, int out_size, void* d_ws, size_t ws_size,
                              hipStream_t stream) {
    const float* X  = (const float*)d_in[0];
    const float* Wq = (const float*)d_in[1];
    const float* Wk = (const float*)d_in[2];
    const float* Wv = (const float*)d_in[3];
    const float* Wo = (const float*)d_in[4];
    float* out = (float*)d_out;
    char* ws = (char*)d_ws;

    bf16* Xb    = (bf16*)(ws);                    // 16 MB (reused as Attn)
    bf16* WqkvT = (bf16*)(ws + (16u << 20));      //  6 MB [3072][1024]
    bf16* WoT   = (bf16*)(ws + (22u << 20));      //  2 MB
    bf16* Qb    = (bf16*)(ws + (24u << 20));      // 16 MB [bh][s][dk] (pre-scaled)
    bf16* Vt    = (bf16*)(ws + (56u << 20));      // 16 MB [bh][dk][s]
    bf16* Attn  = Xb;
    bf16* Kb    = Qb + (size_t)8388608;           // fused-QK second half

    prep_kernel<<<dim3(12288), dim3(256), 0, stream>>>(X, Wq, Wk, Wv, Wo,
                                                       Xb, WqkvT, WoT);

    gemm_qkv<<<dim3(768), dim3(512), 0, stream>>>(Xb, WqkvT, Qb, Vt);

    attn_kernel<<<dim3(1024), dim3(128), 0, stream>>>(Qb, Kb, Vt, Attn);

    gemm_o<<<dim3(512), dim3(256), 0, stream>>>(Attn, WoT, out);
}

// Round 8
// 234.310 us; speedup vs baseline: 1.0736x; 1.0736x over previous
//
#include <hip/hip_runtime.h>

typedef __bf16 bf16;
typedef __attribute__((ext_vector_type(8))) __bf16 bf16x8;
typedef __attribute__((ext_vector_type(4))) float f32x4;
typedef __attribute__((ext_vector_type(16))) float f32x16;
typedef __attribute__((ext_vector_type(4))) unsigned short u16x4;
typedef __attribute__((ext_vector_type(2))) int v2i;

#define D_MODEL 1024
#define SEQ     2048
#define NB      4
#define NH      16
#define DK      64
#define MROWS   (NB * SEQ)   // 8192

#define MFMA_BF16 __builtin_amdgcn_mfma_f32_16x16x32_bf16
#define MFMA32    __builtin_amdgcn_mfma_f32_32x32x16_bf16
#define EXP2F(x) __builtin_amdgcn_exp2f(x)
#define QSCALE 0.18033688011112042f   // 0.125 * log2(e)

__device__ __forceinline__ bf16 f2b(float f) {
    union { float f; unsigned u; } c; c.f = f;
    unsigned r = (c.u + 0x7fffu + ((c.u >> 16) & 1u)) >> 16;
    union { unsigned short s; bf16 b; } o; o.s = (unsigned short)r;
    return o.b;
}
__device__ __forceinline__ unsigned short f2u(float f) {
    union { float f; unsigned u; } c; c.f = f;
    return (unsigned short)((c.u + 0x7fffu + ((c.u >> 16) & 1u)) >> 16);
}

__device__ __forceinline__ f32x16 zero16() {
    f32x16 z = {0.f,0.f,0.f,0.f,0.f,0.f,0.f,0.f,
                0.f,0.f,0.f,0.f,0.f,0.f,0.f,0.f};
    return z;
}

template <int N> struct IC { static constexpr int v = N; };

// ---------------------------------------------------------------- prep (fused)
__global__ void prep_kernel(const float* __restrict__ X,
                            const float* __restrict__ Wq, const float* __restrict__ Wk,
                            const float* __restrict__ Wv, const float* __restrict__ Wo,
                            bf16* __restrict__ Xb, bf16* __restrict__ WqkvT,
                            bf16* __restrict__ WoT) {
    __shared__ float tile[32][33];
    const int bid = blockIdx.x;
    if (bid < 8192) {
        int i = bid * 256 + threadIdx.x;
        float4 v = ((const float4*)X)[i];
        u16x4 o; o[0] = f2u(v.x); o[1] = f2u(v.y); o[2] = f2u(v.z); o[3] = f2u(v.w);
        ((u16x4*)Xb)[i] = o;
    } else {
        int r = bid - 8192;
        int w = r >> 10, tl = r & 1023;
        const float* src = (w == 0) ? Wq : (w == 1) ? Wk : (w == 2) ? Wv : Wo;
        bf16* dst = (w == 3) ? WoT : WqkvT + (size_t)w * 1024 * 1024;
        const int n0 = (tl & 31) * 32, k0 = (tl >> 5) * 32;
        const int tx = threadIdx.x & 31, ty = threadIdx.x >> 5;
#pragma unroll
        for (int i = 0; i < 4; i++)
            tile[ty + i * 8][tx] = src[(size_t)(k0 + ty + i * 8) * 1024 + n0 + tx];
        __syncthreads();
#pragma unroll
        for (int i = 0; i < 4; i++)
            dst[(size_t)(n0 + ty + i * 8) * 1024 + k0 + tx] = f2b(tile[tx][ty + i * 8]);
    }
}

// ---------------------------------------------------------------- fused QKV GEMM
// R17: PERMANENT revert to the R2/R15 config (proven 69.2us, 747 TF, no spill).
// Structural alternatives are closed after 4 failures with 4 distinct causes:
// R12 (frag liveness spill), R13 (residual spill at the 256-reg cliff),
// R14 (drain-pin + 1 block/CU lockstep), R16 (dispatch-order L2 locality loss:
// FETCH 77->200MB at BM256/BN128 grid). The m97 structure + implicit
// wave-overlap at ~3 blocks/CU is this kernel's best HIP-source operating
// point within this session's reach.
__global__ __launch_bounds__(256) void gemm_qkv(const bf16* __restrict__ A,
                                                const bf16* __restrict__ Bt,
                                                bf16* __restrict__ outQ,
                                                bf16* __restrict__ outV) {
    __shared__ __align__(16) bf16 lA[128 * 64];
    __shared__ __align__(16) bf16 lB[128 * 64];

    const int t = threadIdx.x;
    const int wid = t >> 6, lane = t & 63;
    const int ln = lane & 15, qd = lane >> 4;
    const int wm = wid >> 1, wn = wid & 1;

    const int bid = blockIdx.x;
    const int idx = bid >> 3;
    const int colb = (bid & 7) * 3 + (idx % 3);
    const int rowb = idx / 3;
    const int row0 = rowb * 128, col0 = colb * 128;
    const bool isQK = (col0 < 2048);

    const int srow = t >> 3;
    const int schunk = (t & 7) ^ (srow & 7);
    const bf16* ga = A  + (size_t)(row0 + srow) * 1024 + schunk * 8;
    const bf16* gb = Bt + (size_t)(col0 + srow) * 1024 + schunk * 8;
    const int swk = ln & 7;

    f32x4 acc[4][4];
#pragma unroll
    for (int i = 0; i < 4; i++)
#pragma unroll
        for (int j = 0; j < 4; j++) acc[i][j] = (f32x4){0.f, 0.f, 0.f, 0.f};

    for (int kb = 0; kb < 1024; kb += 64) {
#pragma unroll
        for (int c = 0; c < 4; c++) {
            __builtin_amdgcn_global_load_lds(
                (const __attribute__((address_space(1))) void*)(ga + kb + (size_t)c * 32 * 1024),
                (__attribute__((address_space(3))) void*)(&lA[t * 8 + c * 2048]), 16, 0, 0);
            __builtin_amdgcn_global_load_lds(
                (const __attribute__((address_space(1))) void*)(gb + kb + (size_t)c * 32 * 1024),
                (__attribute__((address_space(3))) void*)(&lB[t * 8 + c * 2048]), 16, 0, 0);
        }
        __syncthreads();

#pragma unroll
        for (int ks = 0; ks < 2; ks++) {
            bf16x8 af[4], bfr[4];
#pragma unroll
            for (int i = 0; i < 4; i++)
                af[i] = *(const bf16x8*)&lA[(wm * 64 + i * 16 + ln) * 64
                                            + ((ks * 4 + qd) ^ swk) * 8];
#pragma unroll
            for (int j = 0; j < 4; j++)
                bfr[j] = *(const bf16x8*)&lB[(wn * 64 + j * 16 + ln) * 64
                                             + ((ks * 4 + qd) ^ swk) * 8];
            if (isQK) {
#pragma unroll
                for (int i = 0; i < 4; i++)
#pragma unroll
                    for (int j = 0; j < 4; j++)
                        acc[i][j] = MFMA_BF16(bfr[j], af[i], acc[i][j], 0, 0, 0);
            } else {
#pragma unroll
                for (int i = 0; i < 4; i++)
#pragma unroll
                    for (int j = 0; j < 4; j++)
                        acc[i][j] = MFMA_BF16(af[i], bfr[j], acc[i][j], 0, 0, 0);
            }
        }
        __syncthreads();
    }

    if (isQK) {
#pragma unroll
        for (int i = 0; i < 4; i++)
#pragma unroll
            for (int j = 0; j < 4; j++) {
                int m  = row0 + wm * 64 + i * 16 + ln;
                int n0 = col0 + wn * 64 + j * 16 + qd * 4;
                float scale = (n0 < 1024) ? QSCALE : 1.0f;
                int b = m >> 11, s = m & 2047;
                int h = (n0 & 1023) >> 6, d0 = n0 & 63;
                size_t addr = (((size_t)(b * NH + h) * SEQ + s) * DK + d0)
                              + (size_t)(n0 >> 10) * 8388608;
                u16x4 w;
#pragma unroll
                for (int r = 0; r < 4; r++) w[r] = f2u(acc[i][j][r] * scale);
                *(u16x4*)&outQ[addr] = w;
            }
    } else {
#pragma unroll
        for (int i = 0; i < 4; i++)
#pragma unroll
            for (int j = 0; j < 4; j++) {
                int m0 = row0 + wm * 64 + i * 16 + qd * 4;
                int n  = col0 + wn * 64 + j * 16 + ln - 2048;
                int b = m0 >> 11, s0 = m0 & 2047;
                int h = n >> 6, d = n & 63;
                size_t addr = ((size_t)(b * NH + h) * DK + d) * SEQ + s0;
                u16x4 w;
#pragma unroll
                for (int r = 0; r < 4; r++) w[r] = f2u(acc[i][j][r]);
                *(u16x4*)&outV[addr] = w;
            }
    }
}

// ---------------------------------------------------------------- output GEMM
__global__ __launch_bounds__(256) void gemm_o(const bf16* __restrict__ A,
                                              const bf16* __restrict__ Bt,
                                              float* __restrict__ out) {
    __shared__ __align__(16) bf16 lA[128 * 64];
    __shared__ __align__(16) bf16 lB[128 * 64];

    const int t = threadIdx.x;
    const int wid = t >> 6, lane = t & 63;
    const int ln = lane & 15, qd = lane >> 4;
    const int wm = wid >> 1, wn = wid & 1;

    const int bid = blockIdx.x;
    const int colb = bid & 7, rowb = bid >> 3;
    const int row0 = rowb * 128, col0 = colb * 128;

    const int srow = t >> 3;
    const int schunk = (t & 7) ^ (srow & 7);
    const bf16* ga = A  + (size_t)(row0 + srow) * 1024 + schunk * 8;
    const bf16* gb = Bt + (size_t)(col0 + srow) * 1024 + schunk * 8;
    const int swk = ln & 7;

    f32x4 acc[4][4];
#pragma unroll
    for (int i = 0; i < 4; i++)
#pragma unroll
        for (int j = 0; j < 4; j++) acc[i][j] = (f32x4){0.f, 0.f, 0.f, 0.f};

    for (int kb = 0; kb < 1024; kb += 64) {
#pragma unroll
        for (int c = 0; c < 4; c++) {
            __builtin_amdgcn_global_load_lds(
                (const __attribute__((address_space(1))) void*)(ga + kb + (size_t)c * 32 * 1024),
                (__attribute__((address_space(3))) void*)(&lA[t * 8 + c * 2048]), 16, 0, 0);
            __builtin_amdgcn_global_load_lds(
                (const __attribute__((address_space(1))) void*)(gb + kb + (size_t)c * 32 * 1024),
                (__attribute__((address_space(3))) void*)(&lB[t * 8 + c * 2048]), 16, 0, 0);
        }
        __syncthreads();

#pragma unroll
        for (int ks = 0; ks < 2; ks++) {
            bf16x8 af[4], bfr[4];
#pragma unroll
            for (int i = 0; i < 4; i++)
                af[i] = *(const bf16x8*)&lA[(wm * 64 + i * 16 + ln) * 64
                                            + ((ks * 4 + qd) ^ swk) * 8];
#pragma unroll
            for (int j = 0; j < 4; j++)
                bfr[j] = *(const bf16x8*)&lB[(wn * 64 + j * 16 + ln) * 64
                                             + ((ks * 4 + qd) ^ swk) * 8];
#pragma unroll
            for (int i = 0; i < 4; i++)
#pragma unroll
                for (int j = 0; j < 4; j++)
                    acc[i][j] = MFMA_BF16(bfr[j], af[i], acc[i][j], 0, 0, 0);
        }
        __syncthreads();
    }

#pragma unroll
    for (int i = 0; i < 4; i++)
#pragma unroll
        for (int j = 0; j < 4; j++) {
            int m  = row0 + wm * 64 + i * 16 + ln;
            int n0 = col0 + wn * 64 + j * 16 + qd * 4;
            *(f32x4*)&out[(size_t)m * 1024 + n0] = acc[i][j];
        }
}

// ---------------------------------------------------------------- attention
// R17: R10 structure with 128 q-rows per block (4 waves, 256 thr) instead of
// 64 (2 waves): each K/V tile is staged once per 128 q-rows, halving
// global_load_lds issue count, L2 reads, and LDS write pressure at identical
// per-wave compute. 16 groups of 128 rows, pairs (g, 15-p): every block
// exactly 34 steps. Grid = 64 bh x 8 pairs = 512 blocks = 2 blocks/CU x 4
// waves = 8 waves/CU (same as before; 2 barrier domains/CU).
__global__ __launch_bounds__(256, 2) void attn_kernel(const bf16* __restrict__ Q,
                                                      const bf16* __restrict__ K,
                                                      const bf16* __restrict__ Vt,
                                                      bf16* __restrict__ attn_out) {
    // layout: K buf0 | K buf1 | V buf0 | V buf1   (8 KB each)
    __shared__ __align__(16) bf16 smem[4][64 * 64];

    const int t = threadIdx.x;
    const int wid = t >> 6, lane = t & 63;       // wid 0..3
    const int qcol = lane & 31, h = lane >> 5;

    const int bid = blockIdx.x;
    const int bh = ((bid >> 6) << 3) | (bid & 7);    // XCD-pinned per bh
    const int p  = (bid >> 3) & 7;
    const int gA = 15 - p, gB = p;                   // pair: (2gA+2)+(2gB+2)=34
    const int ntA = 2 * gA + 2;                      // tiles in phase A

    const bf16* Qh = Q  + (size_t)bh * SEQ * DK;
    const bf16* Kh = K  + (size_t)bh * SEQ * DK;
    const bf16* Vh = Vt + (size_t)bh * DK * SEQ;

    // staging pointers (global side pre-swizzled; LDS dest linear)
    const int srow = t >> 3;                         // 0..31
    const int schunk = (t & 7) ^ (srow & 7);
    const bf16* kgp = Kh + (size_t)srow * DK + schunk * 8;
    const bf16* vgp = Vh + (size_t)srow * SEQ + schunk * 8;

    // per-lane ds-read byte addresses: row=qcol, slot XOR-swizzled
    const char* sbase = (const char*)&smem[0][0];
    int raddr[4];
#pragma unroll
    for (int tt = 0; tt < 4; tt++)
        raddr[tt] = qcol * 128 + (((2 * tt + h) ^ (lane & 7)) * 16);

    int qw0;
    bf16x8 qf[4];
    f32x16 o[2];
    float l;

    auto initGroup = [&](int g) {
        qw0 = g * 128 + wid * 32;
#pragma unroll
        for (int tt = 0; tt < 4; tt++)
            qf[tt] = *(const bf16x8*)(Qh + (size_t)(qw0 + qcol) * DK + tt * 16 + h * 8);
        o[0] = zero16(); o[1] = zero16();
        l = 0.f;
    };

    const int b = bh >> 4, head = bh & 15;
    auto finalize = [&]() {
        float ll = l + __shfl_xor(l, 32);
        const float inv = 1.0f / ll;
        const size_t orow = ((size_t)(b * SEQ + qw0 + qcol)) * D_MODEL + head * DK;
#pragma unroll
        for (int m = 0; m < 2; m++)
#pragma unroll
            for (int q4 = 0; q4 < 4; q4++) {
                u16x4 w;
#pragma unroll
                for (int c = 0; c < 4; c++) w[c] = f2u(o[m][q4 * 4 + c] * inv);
                *(u16x4*)&attn_out[orow + m * 32 + q4 * 8 + h * 4] = w;
            }
    };

    // 64x64 K tile (8KB) + 64x64 V tile (8KB); 256 thr x 16B = 4KB/gload
    auto stage = [&](int kb, int buf) {
#pragma unroll
        for (int c = 0; c < 2; c++) {
            __builtin_amdgcn_global_load_lds(
                (const __attribute__((address_space(1))) void*)(kgp + (size_t)(kb + c * 32) * DK),
                (__attribute__((address_space(3))) void*)(&smem[buf][t * 8 + c * 2048]), 16, 0, 0);
            __builtin_amdgcn_global_load_lds(
                (const __attribute__((address_space(1))) void*)(vgp + (size_t)c * 32 * SEQ + kb),
                (__attribute__((address_space(3))) void*)(&smem[2 + buf][t * 8 + c * 2048]), 16, 0, 0);
        }
    };

    // QK^T for one 32-wide k-tile: lane=q, reg=k
    auto qkt = [&](const char* kb_base) -> f32x16 {
        f32x16 z = zero16();
#pragma unroll
        for (int tt = 0; tt < 4; tt++) {
            bf16x8 kf = *(const bf16x8*)(kb_base + raddr[tt]);
            z = MFMA32(kf, qf[tt], z, 0, 0, 0);
        }
        return z;
    };

    // pack 8 P-floats (k-slice ks) -> B-fragment, 2 PV MFMAs
    auto pvks = [&](const f32x16& s, int b8, int ks, const char* vbase) {
        unsigned A, B, C, D;
        asm("v_cvt_pk_bf16_f32 %0, %1, %2"
            : "=v"(A) : "v"(s[b8 + 0]), "v"(s[b8 + 1]));
        asm("v_cvt_pk_bf16_f32 %0, %1, %2"
            : "=v"(B) : "v"(s[b8 + 2]), "v"(s[b8 + 3]));
        asm("v_cvt_pk_bf16_f32 %0, %1, %2"
            : "=v"(C) : "v"(s[b8 + 4]), "v"(s[b8 + 5]));
        asm("v_cvt_pk_bf16_f32 %0, %1, %2"
            : "=v"(D) : "v"(s[b8 + 6]), "v"(s[b8 + 7]));
        v2i r02 = __builtin_amdgcn_permlane32_swap((int)A, (int)C, false, false);
        v2i r13 = __builtin_amdgcn_permlane32_swap((int)B, (int)D, false, false);
        union { unsigned u[4]; bf16x8 v; } pf;
        pf.u[0] = (unsigned)r02[0];
        pf.u[1] = (unsigned)r13[0];
        pf.u[2] = (unsigned)r02[1];
        pf.u[3] = (unsigned)r13[1];
#pragma unroll
        for (int m = 0; m < 2; m++) {
            bf16x8 vf = *(const bf16x8*)(vbase + raddr[ks] + m * 4096);
            o[m] = MFMA32(vf, pf.v, o[m], 0, 0, 0);
        }
    };

    auto smaxFull = [&](f32x16& s) -> float {
#pragma unroll
        for (int r = 0; r < 16; r++) s[r] = EXP2F(s[r]);
        float s0 = (s[0] + s[1]) + (s[2] + s[3]);
        float s1 = (s[4] + s[5]) + (s[6] + s[7]);
        float s2 = (s[8] + s[9]) + (s[10] + s[11]);
        float s3 = (s[12] + s[13]) + (s[14] + s[15]);
        return (s0 + s1) + (s2 + s3);
    };

    auto compute = [&](auto curc, int kb) {
        constexpr int CUR = decltype(curc)::v;
        const char* kbase = sbase + CUR * 8192;
        const char* vbase = sbase + 16384 + CUR * 8192;
        const int rel = qw0 - kb;          // wave-uniform
        if (rel < 0) return;
        if (rel >= 64) {
            // ---- full: both tiles, no causal mask
            __builtin_amdgcn_s_setprio(1);
            f32x16 s0 = qkt(kbase);
            f32x16 s1 = qkt(kbase + 4096);
            __builtin_amdgcn_s_setprio(0);
            l += smaxFull(s0);
            __builtin_amdgcn_s_setprio(1);
            pvks(s0, 0, 0, vbase);
            pvks(s0, 8, 1, vbase);
            __builtin_amdgcn_s_setprio(0);
            l += smaxFull(s1);
            __builtin_amdgcn_s_setprio(1);
            pvks(s1, 0, 2, vbase);
            pvks(s1, 8, 3, vbase);
            __builtin_amdgcn_s_setprio(0);
        } else {
            // ---- edge: nt tiles, diagonal mask on tile n = rel>>5
            const int nt = (rel >> 5) + 1;      // 1 or 2
            f32x16 st[2];
#pragma unroll
            for (int n = 0; n < 2; n++)
                if (n < nt) st[n] = qkt(kbase + n * 4096);
            float ps = 0.f;
#pragma unroll
            for (int n = 0; n < 2; n++)
                if (n < nt) {
                    const bool diag = (rel == 32 * n);
#pragma unroll
                    for (int r = 0; r < 16; r++) {
                        float pv = EXP2F(st[n][r]);
                        if (diag) {
                            const int kloc = (r & 3) + 8 * (r >> 2) + 4 * h;
                            pv = (kloc > qcol) ? 0.f : pv;
                        }
                        st[n][r] = pv;
                    }
                    float s0 = (st[n][0] + st[n][1]) + (st[n][2] + st[n][3]);
                    float s1 = (st[n][4] + st[n][5]) + (st[n][6] + st[n][7]);
                    float s2 = (st[n][8] + st[n][9]) + (st[n][10] + st[n][11]);
                    float s3 = (st[n][12] + st[n][13]) + (st[n][14] + st[n][15]);
                    ps += (s0 + s1) + (s2 + s3);
                }
            l += ps;
#pragma unroll
            for (int ks = 0; ks < 4; ks++)
                if (ks < 2 * nt)
                    pvks(st[ks >> 1], (ks & 1) * 8, ks, vbase);
        }
    };

    auto step = [&](auto curc, int i) {
        constexpr int CUR = decltype(curc)::v;
        __syncthreads();                       // drains prev stage (vmcnt(0))
        const int nx = i + 1;
        if (nx < 34) {
            const int tnx = (nx < ntA) ? nx : nx - ntA;
            stage(tnx * 64, CUR ^ 1);
        }
        const int kb = ((i < ntA) ? i : i - ntA) * 64;
        compute(curc, kb);
        if (i == ntA - 1) { finalize(); initGroup(gB); }
    };

    stage(0, 0);
    initGroup(gA);

    step(IC<0>{}, 0);
#pragma unroll 1
    for (int ii = 0; ii < 16; ii++) {
        step(IC<1>{}, 2 * ii + 1);
        step(IC<0>{}, 2 * ii + 2);
    }
    step(IC<1>{}, 33);
    finalize();
}

// ---------------------------------------------------------------- launch
extern "C" void kernel_launch(void* const* d_in, const int* in_sizes, int n_in,
                              void* d_out, int out_size, void* d_ws, size_t ws_size,
                              hipStream_t stream) {
    const float* X  = (const float*)d_in[0];
    const float* Wq = (const float*)d_in[1];
    const float* Wk = (const float*)d_in[2];
    const float* Wv = (const float*)d_in[3];
    const float* Wo = (const float*)d_in[4];
    float* out = (float*)d_out;
    char* ws = (char*)d_ws;

    bf16* Xb    = (bf16*)(ws);                    // 16 MB (reused as Attn)
    bf16* WqkvT = (bf16*)(ws + (16u << 20));      //  6 MB [3072][1024]
    bf16* WoT   = (bf16*)(ws + (22u << 20));      //  2 MB
    bf16* Qb    = (bf16*)(ws + (24u << 20));      // 16 MB [bh][s][dk] (pre-scaled)
    bf16* Vt    = (bf16*)(ws + (56u << 20));      // 16 MB [bh][dk][s]
    bf16* Attn  = Xb;
    bf16* Kb    = Qb + (size_t)8388608;           // fused-QK second half

    prep_kernel<<<dim3(12288), dim3(256), 0, stream>>>(X, Wq, Wk, Wv, Wo,
                                                       Xb, WqkvT, WoT);

    gemm_qkv<<<dim3(1536), dim3(256), 0, stream>>>(Xb, WqkvT, Qb, Vt);

    attn_kernel<<<dim3(512), dim3(256), 0, stream>>>(Qb, Kb, Vt, Attn);

    gemm_o<<<dim3(512), dim3(256), 0, stream>>>(Attn, WoT, out);
}

// Round 9
// 234.108 us; speedup vs baseline: 1.0745x; 1.0009x over previous
//
#include <hip/hip_runtime.h>

typedef __bf16 bf16;
typedef __attribute__((ext_vector_type(8))) __bf16 bf16x8;
typedef __attribute__((ext_vector_type(4))) float f32x4;
typedef __attribute__((ext_vector_type(16))) float f32x16;
typedef __attribute__((ext_vector_type(4))) unsigned short u16x4;
typedef __attribute__((ext_vector_type(2))) int v2i;

#define D_MODEL 1024
#define SEQ     2048
#define NB      4
#define NH      16
#define DK      64
#define MROWS   (NB * SEQ)   // 8192

#define MFMA_BF16 __builtin_amdgcn_mfma_f32_16x16x32_bf16
#define MFMA32    __builtin_amdgcn_mfma_f32_32x32x16_bf16
#define EXP2F(x) __builtin_amdgcn_exp2f(x)
#define QSCALE 0.18033688011112042f   // 0.125 * log2(e)

__device__ __forceinline__ bf16 f2b(float f) {
    union { float f; unsigned u; } c; c.f = f;
    unsigned r = (c.u + 0x7fffu + ((c.u >> 16) & 1u)) >> 16;
    union { unsigned short s; bf16 b; } o; o.s = (unsigned short)r;
    return o.b;
}
__device__ __forceinline__ unsigned short f2u(float f) {
    union { float f; unsigned u; } c; c.f = f;
    return (unsigned short)((c.u + 0x7fffu + ((c.u >> 16) & 1u)) >> 16);
}

__device__ __forceinline__ f32x16 zero16() {
    f32x16 z = {0.f,0.f,0.f,0.f,0.f,0.f,0.f,0.f,
                0.f,0.f,0.f,0.f,0.f,0.f,0.f,0.f};
    return z;
}

template <int N> struct IC { static constexpr int v = N; };

// ---------------------------------------------------------------- prep (fused)
// R18: W-transpose writes vectorized (u16x4 per thread, 4x fewer write
// transactions vs scalar 2B stores). Mapping unchanged: dst[n][k] = src[k][n].
__global__ void prep_kernel(const float* __restrict__ X,
                            const float* __restrict__ Wq, const float* __restrict__ Wk,
                            const float* __restrict__ Wv, const float* __restrict__ Wo,
                            bf16* __restrict__ Xb, bf16* __restrict__ WqkvT,
                            bf16* __restrict__ WoT) {
    __shared__ float tile[32][33];
    const int bid = blockIdx.x;
    if (bid < 8192) {
        int i = bid * 256 + threadIdx.x;
        float4 v = ((const float4*)X)[i];
        u16x4 o; o[0] = f2u(v.x); o[1] = f2u(v.y); o[2] = f2u(v.z); o[3] = f2u(v.w);
        ((u16x4*)Xb)[i] = o;
    } else {
        int r = bid - 8192;
        int w = r >> 10, tl = r & 1023;
        const float* src = (w == 0) ? Wq : (w == 1) ? Wk : (w == 2) ? Wv : Wo;
        bf16* dst = (w == 3) ? WoT : WqkvT + (size_t)w * 1024 * 1024;
        const int n0 = (tl & 31) * 32, k0 = (tl >> 5) * 32;
        const int tx = threadIdx.x & 31, ty = threadIdx.x >> 5;
#pragma unroll
        for (int i = 0; i < 4; i++)
            tile[ty + i * 8][tx] = src[(size_t)(k0 + ty + i * 8) * 1024 + n0 + tx];
        __syncthreads();
        const int n4 = threadIdx.x >> 3;        // 0..31
        const int k4 = (threadIdx.x & 7) * 4;   // 0,4,..,28
        u16x4 ww;
#pragma unroll
        for (int j = 0; j < 4; j++) ww[j] = f2u(tile[k4 + j][n4]);
        *(u16x4*)&dst[(size_t)(n0 + n4) * 1024 + k0 + k4] = ww;
    }
}

// ---------------------------------------------------------------- fused QKV GEMM
// R15/R17 config kept permanently (proven 69.2us, 747 TF, no spill).
// Structural alternatives closed after 4 failures with 4 distinct causes
// (R12 frag-liveness spill, R13 256-reg-cliff spill, R14 drain-pin +
// 1 block/CU lockstep, R16 dispatch-order L2 locality loss).
__global__ __launch_bounds__(256) void gemm_qkv(const bf16* __restrict__ A,
                                                const bf16* __restrict__ Bt,
                                                bf16* __restrict__ outQ,
                                                bf16* __restrict__ outV) {
    __shared__ __align__(16) bf16 lA[128 * 64];
    __shared__ __align__(16) bf16 lB[128 * 64];

    const int t = threadIdx.x;
    const int wid = t >> 6, lane = t & 63;
    const int ln = lane & 15, qd = lane >> 4;
    const int wm = wid >> 1, wn = wid & 1;

    const int bid = blockIdx.x;
    const int idx = bid >> 3;
    const int colb = (bid & 7) * 3 + (idx % 3);
    const int rowb = idx / 3;
    const int row0 = rowb * 128, col0 = colb * 128;
    const bool isQK = (col0 < 2048);

    const int srow = t >> 3;
    const int schunk = (t & 7) ^ (srow & 7);
    const bf16* ga = A  + (size_t)(row0 + srow) * 1024 + schunk * 8;
    const bf16* gb = Bt + (size_t)(col0 + srow) * 1024 + schunk * 8;
    const int swk = ln & 7;

    f32x4 acc[4][4];
#pragma unroll
    for (int i = 0; i < 4; i++)
#pragma unroll
        for (int j = 0; j < 4; j++) acc[i][j] = (f32x4){0.f, 0.f, 0.f, 0.f};

    for (int kb = 0; kb < 1024; kb += 64) {
#pragma unroll
        for (int c = 0; c < 4; c++) {
            __builtin_amdgcn_global_load_lds(
                (const __attribute__((address_space(1))) void*)(ga + kb + (size_t)c * 32 * 1024),
                (__attribute__((address_space(3))) void*)(&lA[t * 8 + c * 2048]), 16, 0, 0);
            __builtin_amdgcn_global_load_lds(
                (const __attribute__((address_space(1))) void*)(gb + kb + (size_t)c * 32 * 1024),
                (__attribute__((address_space(3))) void*)(&lB[t * 8 + c * 2048]), 16, 0, 0);
        }
        __syncthreads();

#pragma unroll
        for (int ks = 0; ks < 2; ks++) {
            bf16x8 af[4], bfr[4];
#pragma unroll
            for (int i = 0; i < 4; i++)
                af[i] = *(const bf16x8*)&lA[(wm * 64 + i * 16 + ln) * 64
                                            + ((ks * 4 + qd) ^ swk) * 8];
#pragma unroll
            for (int j = 0; j < 4; j++)
                bfr[j] = *(const bf16x8*)&lB[(wn * 64 + j * 16 + ln) * 64
                                             + ((ks * 4 + qd) ^ swk) * 8];
            if (isQK) {
#pragma unroll
                for (int i = 0; i < 4; i++)
#pragma unroll
                    for (int j = 0; j < 4; j++)
                        acc[i][j] = MFMA_BF16(bfr[j], af[i], acc[i][j], 0, 0, 0);
            } else {
#pragma unroll
                for (int i = 0; i < 4; i++)
#pragma unroll
                    for (int j = 0; j < 4; j++)
                        acc[i][j] = MFMA_BF16(af[i], bfr[j], acc[i][j], 0, 0, 0);
            }
        }
        __syncthreads();
    }

    if (isQK) {
#pragma unroll
        for (int i = 0; i < 4; i++)
#pragma unroll
            for (int j = 0; j < 4; j++) {
                int m  = row0 + wm * 64 + i * 16 + ln;
                int n0 = col0 + wn * 64 + j * 16 + qd * 4;
                float scale = (n0 < 1024) ? QSCALE : 1.0f;
                int b = m >> 11, s = m & 2047;
                int h = (n0 & 1023) >> 6, d0 = n0 & 63;
                size_t addr = (((size_t)(b * NH + h) * SEQ + s) * DK + d0)
                              + (size_t)(n0 >> 10) * 8388608;
                u16x4 w;
#pragma unroll
                for (int r = 0; r < 4; r++) w[r] = f2u(acc[i][j][r] * scale);
                *(u16x4*)&outQ[addr] = w;
            }
    } else {
#pragma unroll
        for (int i = 0; i < 4; i++)
#pragma unroll
            for (int j = 0; j < 4; j++) {
                int m0 = row0 + wm * 64 + i * 16 + qd * 4;
                int n  = col0 + wn * 64 + j * 16 + ln - 2048;
                int b = m0 >> 11, s0 = m0 & 2047;
                int h = n >> 6, d = n & 63;
                size_t addr = ((size_t)(b * NH + h) * DK + d) * SEQ + s0;
                u16x4 w;
#pragma unroll
                for (int r = 0; r < 4; r++) w[r] = f2u(acc[i][j][r]);
                *(u16x4*)&outV[addr] = w;
            }
    }
}

// ---------------------------------------------------------------- output GEMM
__global__ __launch_bounds__(256) void gemm_o(const bf16* __restrict__ A,
                                              const bf16* __restrict__ Bt,
                                              float* __restrict__ out) {
    __shared__ __align__(16) bf16 lA[128 * 64];
    __shared__ __align__(16) bf16 lB[128 * 64];

    const int t = threadIdx.x;
    const int wid = t >> 6, lane = t & 63;
    const int ln = lane & 15, qd = lane >> 4;
    const int wm = wid >> 1, wn = wid & 1;

    const int bid = blockIdx.x;
    const int colb = bid & 7, rowb = bid >> 3;
    const int row0 = rowb * 128, col0 = colb * 128;

    const int srow = t >> 3;
    const int schunk = (t & 7) ^ (srow & 7);
    const bf16* ga = A  + (size_t)(row0 + srow) * 1024 + schunk * 8;
    const bf16* gb = Bt + (size_t)(col0 + srow) * 1024 + schunk * 8;
    const int swk = ln & 7;

    f32x4 acc[4][4];
#pragma unroll
    for (int i = 0; i < 4; i++)
#pragma unroll
        for (int j = 0; j < 4; j++) acc[i][j] = (f32x4){0.f, 0.f, 0.f, 0.f};

    for (int kb = 0; kb < 1024; kb += 64) {
#pragma unroll
        for (int c = 0; c < 4; c++) {
            __builtin_amdgcn_global_load_lds(
                (const __attribute__((address_space(1))) void*)(ga + kb + (size_t)c * 32 * 1024),
                (__attribute__((address_space(3))) void*)(&lA[t * 8 + c * 2048]), 16, 0, 0);
            __builtin_amdgcn_global_load_lds(
                (const __attribute__((address_space(1))) void*)(gb + kb + (size_t)c * 32 * 1024),
                (__attribute__((address_space(3))) void*)(&lB[t * 8 + c * 2048]), 16, 0, 0);
        }
        __syncthreads();

#pragma unroll
        for (int ks = 0; ks < 2; ks++) {
            bf16x8 af[4], bfr[4];
#pragma unroll
            for (int i = 0; i < 4; i++)
                af[i] = *(const bf16x8*)&lA[(wm * 64 + i * 16 + ln) * 64
                                            + ((ks * 4 + qd) ^ swk) * 8];
#pragma unroll
            for (int j = 0; j < 4; j++)
                bfr[j] = *(const bf16x8*)&lB[(wn * 64 + j * 16 + ln) * 64
                                             + ((ks * 4 + qd) ^ swk) * 8];
#pragma unroll
            for (int i = 0; i < 4; i++)
#pragma unroll
                for (int j = 0; j < 4; j++)
                    acc[i][j] = MFMA_BF16(bfr[j], af[i], acc[i][j], 0, 0, 0);
        }
        __syncthreads();
    }

#pragma unroll
    for (int i = 0; i < 4; i++)
#pragma unroll
        for (int j = 0; j < 4; j++) {
            int m  = row0 + wm * 64 + i * 16 + ln;
            int n0 = col0 + wn * 64 + j * 16 + qd * 4;
            *(f32x4*)&out[(size_t)m * 1024 + n0] = acc[i][j];
        }
}

// ---------------------------------------------------------------- attention
// R18: KVBLK=128 per step. Each step stages one 128-row K tile (16KB) + the
// matching V tile (2 seq-halves of [64dk][64seq], 8KB apart) into a 32KB
// double-buffer set (LDS 64KB total, 2 blocks/CU unchanged), then computes
// the two 64-KV halves back-to-back with the proven R17 body. Steps per
// block: 34 -> 17 (halved barrier/drain count). Pairs (gA=15-p, gB=p) of
// 128-row q-groups: uniform 17 steps per block; grid 512.
__global__ __launch_bounds__(256, 2) void attn_kernel(const bf16* __restrict__ Q,
                                                      const bf16* __restrict__ K,
                                                      const bf16* __restrict__ Vt,
                                                      bf16* __restrict__ attn_out) {
    // layout: K buf0 | K buf1 | V buf0 | V buf1   (16 KB each)
    __shared__ __align__(16) bf16 smem[4][128 * 64];

    const int t = threadIdx.x;
    const int wid = t >> 6, lane = t & 63;       // wid 0..3
    const int qcol = lane & 31, h = lane >> 5;

    const int bid = blockIdx.x;
    const int bh = ((bid >> 6) << 3) | (bid & 7);    // XCD-pinned per bh
    const int p  = (bid >> 3) & 7;
    const int gA = 15 - p, gB = p;                   // (gA+1)+(gB+1) = 17 steps
    const int ntA = gA + 1;                          // 128-wide tiles in phase A

    const bf16* Qh = Q  + (size_t)bh * SEQ * DK;
    const bf16* Kh = K  + (size_t)bh * SEQ * DK;
    const bf16* Vh = Vt + (size_t)bh * DK * SEQ;

    // staging pointers (global side pre-swizzled; LDS dest linear)
    const int srow = t >> 3;                         // 0..31
    const int schunk = (t & 7) ^ (srow & 7);
    const bf16* kgp = Kh + (size_t)srow * DK + schunk * 8;
    const bf16* vgp = Vh + (size_t)srow * SEQ + schunk * 8;

    // per-lane ds-read byte addresses: row=qcol, slot XOR-swizzled
    const char* sbase = (const char*)&smem[0][0];
    int raddr[4];
#pragma unroll
    for (int tt = 0; tt < 4; tt++)
        raddr[tt] = qcol * 128 + (((2 * tt + h) ^ (lane & 7)) * 16);

    int qw0;
    bf16x8 qf[4];
    f32x16 o[2];
    float l;

    auto initGroup = [&](int g) {
        qw0 = g * 128 + wid * 32;
#pragma unroll
        for (int tt = 0; tt < 4; tt++)
            qf[tt] = *(const bf16x8*)(Qh + (size_t)(qw0 + qcol) * DK + tt * 16 + h * 8);
        o[0] = zero16(); o[1] = zero16();
        l = 0.f;
    };

    const int b = bh >> 4, head = bh & 15;
    auto finalize = [&]() {
        float ll = l + __shfl_xor(l, 32);
        const float inv = 1.0f / ll;
        const size_t orow = ((size_t)(b * SEQ + qw0 + qcol)) * D_MODEL + head * DK;
#pragma unroll
        for (int m = 0; m < 2; m++)
#pragma unroll
            for (int q4 = 0; q4 < 4; q4++) {
                u16x4 w;
#pragma unroll
                for (int c = 0; c < 4; c++) w[c] = f2u(o[m][q4 * 4 + c] * inv);
                *(u16x4*)&attn_out[orow + m * 32 + q4 * 8 + h * 4] = w;
            }
    };

    // K: 128 rows x 64 dk = 16KB (4 gloads); V: 2 seq-halves of [64dk][64seq]
    // at +0 / +8KB (4 gloads). 256 thr x 16B = 4KB per gload.
    auto stage = [&](int kb, int buf) {
#pragma unroll
        for (int c = 0; c < 4; c++)
            __builtin_amdgcn_global_load_lds(
                (const __attribute__((address_space(1))) void*)(kgp + (size_t)(kb + c * 32) * DK),
                (__attribute__((address_space(3))) void*)(&smem[buf][t * 8 + c * 2048]), 16, 0, 0);
#pragma unroll
        for (int hh = 0; hh < 2; hh++)
#pragma unroll
            for (int c = 0; c < 2; c++)
                __builtin_amdgcn_global_load_lds(
                    (const __attribute__((address_space(1))) void*)
                        (vgp + (size_t)c * 32 * SEQ + kb + hh * 64),
                    (__attribute__((address_space(3))) void*)
                        (&smem[2 + buf][t * 8 + hh * 4096 + c * 2048]), 16, 0, 0);
    };

    // QK^T for one 32-wide k-tile: lane=q, reg=k
    auto qkt = [&](const char* kb_base) -> f32x16 {
        f32x16 z = zero16();
#pragma unroll
        for (int tt = 0; tt < 4; tt++) {
            bf16x8 kf = *(const bf16x8*)(kb_base + raddr[tt]);
            z = MFMA32(kf, qf[tt], z, 0, 0, 0);
        }
        return z;
    };

    // pack 8 P-floats (k-slice ks) -> B-fragment, 2 PV MFMAs
    auto pvks = [&](const f32x16& s, int b8, int ks, const char* vbase) {
        unsigned A, B, C, D;
        asm("v_cvt_pk_bf16_f32 %0, %1, %2"
            : "=v"(A) : "v"(s[b8 + 0]), "v"(s[b8 + 1]));
        asm("v_cvt_pk_bf16_f32 %0, %1, %2"
            : "=v"(B) : "v"(s[b8 + 2]), "v"(s[b8 + 3]));
        asm("v_cvt_pk_bf16_f32 %0, %1, %2"
            : "=v"(C) : "v"(s[b8 + 4]), "v"(s[b8 + 5]));
        asm("v_cvt_pk_bf16_f32 %0, %1, %2"
            : "=v"(D) : "v"(s[b8 + 6]), "v"(s[b8 + 7]));
        v2i r02 = __builtin_amdgcn_permlane32_swap((int)A, (int)C, false, false);
        v2i r13 = __builtin_amdgcn_permlane32_swap((int)B, (int)D, false, false);
        union { unsigned u[4]; bf16x8 v; } pf;
        pf.u[0] = (unsigned)r02[0];
        pf.u[1] = (unsigned)r13[0];
        pf.u[2] = (unsigned)r02[1];
        pf.u[3] = (unsigned)r13[1];
#pragma unroll
        for (int m = 0; m < 2; m++) {
            bf16x8 vf = *(const bf16x8*)(vbase + raddr[ks] + m * 4096);
            o[m] = MFMA32(vf, pf.v, o[m], 0, 0, 0);
        }
    };

    auto smaxFull = [&](f32x16& s) -> float {
#pragma unroll
        for (int r = 0; r < 16; r++) s[r] = EXP2F(s[r]);
        float s0 = (s[0] + s[1]) + (s[2] + s[3]);
        float s1 = (s[4] + s[5]) + (s[6] + s[7]);
        float s2 = (s[8] + s[9]) + (s[10] + s[11]);
        float s3 = (s[12] + s[13]) + (s[14] + s[15]);
        return (s0 + s1) + (s2 + s3);
    };

    auto compute = [&](auto curc, int kb) {
        constexpr int CUR = decltype(curc)::v;
        const char* kT = sbase + CUR * 16384;
        const char* vT = sbase + 32768 + CUR * 16384;
#pragma unroll
        for (int half = 0; half < 2; half++) {
            const char* kbase = kT + half * 8192;
            const char* vbase = vT + half * 8192;
            const int rel = qw0 - (kb + half * 64);   // wave-uniform
            if (rel < 0) continue;
            if (rel >= 64) {
                // ---- full: both 32-tiles, no causal mask
                __builtin_amdgcn_s_setprio(1);
                f32x16 s0 = qkt(kbase);
                f32x16 s1 = qkt(kbase + 4096);
                __builtin_amdgcn_s_setprio(0);
                l += smaxFull(s0);
                __builtin_amdgcn_s_setprio(1);
                pvks(s0, 0, 0, vbase);
                pvks(s0, 8, 1, vbase);
                __builtin_amdgcn_s_setprio(0);
                l += smaxFull(s1);
                __builtin_amdgcn_s_setprio(1);
                pvks(s1, 0, 2, vbase);
                pvks(s1, 8, 3, vbase);
                __builtin_amdgcn_s_setprio(0);
            } else {
                // ---- edge: nt 32-tiles, diagonal mask on tile n = rel>>5
                const int nt = (rel >> 5) + 1;      // 1 or 2
                f32x16 st[2];
#pragma unroll
                for (int n = 0; n < 2; n++)
                    if (n < nt) st[n] = qkt(kbase + n * 4096);
                float ps = 0.f;
#pragma unroll
                for (int n = 0; n < 2; n++)
                    if (n < nt) {
                        const bool diag = (rel == 32 * n);
#pragma unroll
                        for (int r = 0; r < 16; r++) {
                            float pv = EXP2F(st[n][r]);
                            if (diag) {
                                const int kloc = (r & 3) + 8 * (r >> 2) + 4 * h;
                                pv = (kloc > qcol) ? 0.f : pv;
                            }
                            st[n][r] = pv;
                        }
                        float s0 = (st[n][0] + st[n][1]) + (st[n][2] + st[n][3]);
                        float s1 = (st[n][4] + st[n][5]) + (st[n][6] + st[n][7]);
                        float s2 = (st[n][8] + st[n][9]) + (st[n][10] + st[n][11]);
                        float s3 = (st[n][12] + st[n][13]) + (st[n][14] + st[n][15]);
                        ps += (s0 + s1) + (s2 + s3);
                    }
                l += ps;
#pragma unroll
                for (int ks = 0; ks < 4; ks++)
                    if (ks < 2 * nt)
                        pvks(st[ks >> 1], (ks & 1) * 8, ks, vbase);
            }
        }
    };

    auto step = [&](auto curc, int i) {
        constexpr int CUR = decltype(curc)::v;
        __syncthreads();                       // drains prev stage (vmcnt(0))
        const int nx = i + 1;
        if (nx < 17) {
            const int tnx = (nx < ntA) ? nx : nx - ntA;
            stage(tnx * 128, CUR ^ 1);
        }
        const int kb = ((i < ntA) ? i : i - ntA) * 128;
        compute(curc, kb);
        if (i == ntA - 1) { finalize(); initGroup(gB); }
    };

    stage(0, 0);
    initGroup(gA);

    step(IC<0>{}, 0);
#pragma unroll 1
    for (int ii = 0; ii < 8; ii++) {
        step(IC<1>{}, 2 * ii + 1);
        step(IC<0>{}, 2 * ii + 2);
    }
    finalize();
}

// ---------------------------------------------------------------- launch
extern "C" void kernel_launch(void* const* d_in, const int* in_sizes, int n_in,
                              void* d_out, int out_size, void* d_ws, size_t ws_size,
                              hipStream_t stream) {
    const float* X  = (const float*)d_in[0];
    const float* Wq = (const float*)d_in[1];
    const float* Wk = (const float*)d_in[2];
    const float* Wv = (const float*)d_in[3];
    const float* Wo = (const float*)d_in[4];
    float* out = (float*)d_out;
    char* ws = (char*)d_ws;

    bf16* Xb    = (bf16*)(ws);                    // 16 MB (reused as Attn)
    bf16* WqkvT = (bf16*)(ws + (16u << 20));      //  6 MB [3072][1024]
    bf16* WoT   = (bf16*)(ws + (22u << 20));      //  2 MB
    bf16* Qb    = (bf16*)(ws + (24u << 20));      // 16 MB [bh][s][dk] (pre-scaled)
    bf16* Vt    = (bf16*)(ws + (56u << 20));      // 16 MB [bh][dk][s]
    bf16* Attn  = Xb;
    bf16* Kb    = Qb + (size_t)8388608;           // fused-QK second half

    prep_kernel<<<dim3(12288), dim3(256), 0, stream>>>(X, Wq, Wk, Wv, Wo,
                                                       Xb, WqkvT, WoT);

    gemm_qkv<<<dim3(1536), dim3(256), 0, stream>>>(Xb, WqkvT, Qb, Vt);

    attn_kernel<<<dim3(512), dim3(256), 0, stream>>>(Qb, Kb, Vt, Attn);

    gemm_o<<<dim3(512), dim3(256), 0, stream>>>(Attn, WoT, out);
}